// Round 10
// baseline (222.924 us; speedup 1.0000x reference)
//
#include <hip/hip_runtime.h>

// ---------------- types ----------------
typedef __attribute__((ext_vector_type(8)))  __bf16 bf16x8;
typedef __attribute__((ext_vector_type(16))) float  f32x16;

struct U4 { unsigned int x, y, z, w; };

// pack two floats to bf16x2 (compiler fuses to v_cvt_pk_bf16_f32, RNE)
static __device__ __forceinline__ unsigned pk2(float lo, float hi){
  unsigned short ul = __builtin_bit_cast(unsigned short, (__bf16)lo);
  unsigned short uh = __builtin_bit_cast(unsigned short, (__bf16)hi);
  return (unsigned)ul | ((unsigned)uh << 16);
}

static __device__ __forceinline__ bf16x8 ldfrag(const void* p){
  U4 v = *(const U4*)p;                      // ds_read_b128
  return __builtin_bit_cast(bf16x8, v);
}

static __device__ __forceinline__ f32x16 mfma32(bf16x8 a, bf16x8 b, f32x16 c){
  return __builtin_amdgcn_mfma_f32_32x32x16_bf16(a, b, c, 0, 0, 0);
}

static __device__ __forceinline__ f32x16 zero16(){
  f32x16 z;
#pragma unroll
  for (int i = 0; i < 16; ++i) z[i] = 0.0f;
  return z;
}

// half-wave swap via permlane (VALU-only, no LDS)
static __device__ __forceinline__ void swap32(unsigned &a, unsigned &b){
  asm volatile("v_permlane32_swap_b32 %0, %1" : "+v"(a), "+v"(b));
}

// async 16B global -> LDS (linear: wave-uniform base + lane*16; R3-verified)
static __device__ __forceinline__ void gload16(const void* g, void* l){
  __builtin_amdgcn_global_load_lds(
      (const __attribute__((address_space(1))) unsigned int*)g,
      (__attribute__((address_space(3))) unsigned int*)l, 16, 0, 0);
}

// ---------------- constants ----------------
// B=8 T=2048 E=8 D=128 H=512 ; token-expert rows = 131072
#define IMG_EC  49152           // 48 KB per (expert, chunk): wg 16K | wu 16K | wd 16K

// ---------------- P1: absmean sums ----------------
__global__ void k_gamma(const float* __restrict__ gw, const float* __restrict__ uw,
                        const float* __restrict__ dw, float* __restrict__ sums){
  int t = blockIdx.y;
  const float* w = (t == 0) ? gw : (t == 1 ? uw : dw);
  int base = blockIdx.x * 2048 + threadIdx.x * 8;
  float4 a = *(const float4*)(w + base);
  float4 b = *(const float4*)(w + base + 4);
  float s = fabsf(a.x)+fabsf(a.y)+fabsf(a.z)+fabsf(a.w)
          + fabsf(b.x)+fabsf(b.y)+fabsf(b.z)+fabsf(b.w);
#pragma unroll
  for (int o = 32; o; o >>= 1) s += __shfl_xor(s, o);
  if ((threadIdx.x & 63) == 0) atomicAdd(&sums[t], s);
}

// ---------------- P2: ternary quantize -> fragment-ordered bf16 images ----------------
// gate/up image per (e,c): [ht(2)][ks(8)][lane(64)][16B]  (frag: h = ht*32+(L&31), k d = ks*16+(L>>5)*8+j)
// down    image per (e,c): [dt(4)][ksp(4)][lane(64)][16B] (frag: d = dt*32+(L&31), k h = c*64+ksp*16+(L>>5)*8+j)
__global__ void k_quant(const float* __restrict__ gw, const float* __restrict__ uw,
                        const float* __restrict__ dw, const float* __restrict__ sums,
                        unsigned char* __restrict__ img){
  int b  = blockIdx.x;
  int tt = b % 3;
  int c  = (b / 3) & 7;
  int e  = b / 24;
  const float* w = (tt == 0) ? gw : (tt == 1 ? uw : dw);
  float inv = 1.0f / (sums[tt] * (1.0f / 524288.0f) + 1e-8f);
  unsigned char* dst = img + (size_t)(e * 8 + c) * IMG_EC + tt * 16384;
#pragma unroll
  for (int i = 0; i < 4; ++i){
    int grp = threadIdx.x + i * 256;      // 0..1023 (16B groups of 16KB)
    int L = grp & 63, blkid = grp >> 6;
    int srcoff;
    if (tt < 2){
      int ht = blkid >> 3, ks = blkid & 7;
      int h  = c * 64 + ht * 32 + (L & 31);
      int dd = ks * 16 + (L >> 5) * 8;
      srcoff = (e * 512 + h) * 128 + dd;
    } else {
      int dt = blkid >> 2, ksp = blkid & 3;
      int d0 = dt * 32 + (L & 31);
      int h  = c * 64 + ksp * 16 + (L >> 5) * 8;
      srcoff = (e * 128 + d0) * 512 + h;
    }
    float4 f0 = *(const float4*)(w + srcoff);
    float4 f1 = *(const float4*)(w + srcoff + 4);
    float v[8] = {f0.x,f0.y,f0.z,f0.w,f1.x,f1.y,f1.z,f1.w};
    unsigned int o[4];
#pragma unroll
    for (int j = 0; j < 4; ++j){
      float q0 = fminf(1.0f, fmaxf(-1.0f, rintf(v[2*j]   * inv)));
      float q1 = fminf(1.0f, fmaxf(-1.0f, rintf(v[2*j+1] * inv)));
      o[j] = pk2(q0, q1);
    }
    *(U4*)(dst + grp * 16) = U4{o[0], o[1], o[2], o[3]};
  }
}

// ---------------- main fused kernel ----------------
// grid (64, 8), 512 threads (8 waves), wave owns 32 tokens.
// Swapped mm1: C = mfma(W, x^T) -> col = token; hidden stays in registers
// (cvt_pk + permlane32_swap) feeding mm2 B-frags directly.
// 2-chunk phases (96 KB LDS): write phase stages chunk 2p via ds_write (from
// stg regs) AND chunk 2p+1 via global_load_lds DMA (zero registers); both
// barrier-isolated from reads. Compute runs both chunks back-to-back.
// Barriers 16 -> 8, write-phases 8 -> 4, double latency-hiding per phase.
// (2,2): the only register regime that never spills (R3/R6 WRITE=65.5MB;
// all of bare/(2,3)/(3,3)/(4,4) demoted stg[] to scratch: 124-417MB storms).
__global__ __attribute__((amdgpu_waves_per_eu(2, 2))) __launch_bounds__(512)
void k_moe(const float* __restrict__ x, const float* __restrict__ ew,
           const float* __restrict__ sums, const unsigned char* __restrict__ img,
           float* __restrict__ out){
  extern __shared__ char smem[];          // [0,48K) even chunk | [48K,96K) odd
  const int tile = blockIdx.x;
  const int e    = blockIdx.y;
  const int tid  = threadIdx.x;
  const int lane = tid & 63;
  const int wid  = tid >> 6;
  const int col  = lane & 31;
  const int hi   = lane >> 5;
  const int token = tile * 256 + wid * 32 + col;

  const float gg  = sums[0] * (1.0f/524288.0f) + 1e-8f;
  const float gu  = sums[1] * (1.0f/524288.0f) + 1e-8f;
  const float gdn = sums[2] * (1.0f/524288.0f) + 1e-8f;

  const unsigned char* wsrc0 = img + (size_t)e * 8 * IMG_EC;

  // ---- preload chunk 0 into stg ----
  U4 stg[6];
#pragma unroll
  for (int k = 0; k < 6; ++k)
    stg[k] = *(const U4*)(wsrc0 + tid * 16 + k * 8192);

  // ---- x fragments in registers: lane holds x[token][ks*16 + hi*8 .. +8) ----
  const float* xrow = x + ((size_t)token * 8 + e) * 128 + hi * 8;
  bf16x8 xf[8];
#pragma unroll
  for (int ks = 0; ks < 8; ++ks){
    float4 f0 = *(const float4*)(xrow + ks * 16);
    float4 f1 = *(const float4*)(xrow + ks * 16 + 4);
    U4 u{pk2(f0.x,f0.y), pk2(f0.z,f0.w), pk2(f1.x,f1.y), pk2(f1.z,f1.w)};
    xf[ks] = __builtin_bit_cast(bf16x8, u);
  }

  f32x16 O0 = zero16(), O1 = zero16(), O2 = zero16(), O3 = zero16();

#pragma unroll
  for (int p = 0; p < 4; ++p){
    // ---- write phase (barrier-isolated from all reads) ----
    if (p) __syncthreads();               // compute(p-1) done reading smem
    // even chunk 2p from registers
#pragma unroll
    for (int k = 0; k < 6; ++k)
      *(U4*)(smem + tid * 16 + k * 8192) = stg[k];
    // odd chunk 2p+1 via DMA (no registers)
    {
      const unsigned char* cs = wsrc0 + (size_t)(2 * p + 1) * IMG_EC;
#pragma unroll
      for (int k = 0; k < 6; ++k)
        gload16(cs + (size_t)(tid + k * 512) * 16,
                smem + 49152 + (tid + k * 512) * 16);
    }
    __syncthreads();                      // drains lgkm + vmcnt: both ready

    // ---- issue chunk 2p+2 loads; whole double-compute hides them ----
    if (p < 3){
      const unsigned char* cs = wsrc0 + (size_t)(2 * p + 2) * IMG_EC;
#pragma unroll
      for (int k = 0; k < 6; ++k)
        stg[k] = *(const U4*)(cs + tid * 16 + k * 8192);
    }

    // ---- compute both chunks back-to-back ----
#pragma unroll
    for (int half = 0; half < 2; ++half){
      const char* WB = smem + half * 49152;

      // mm1 per 32-h half + silu -> hf (in-register hidden)
      bf16x8 hf[4];
#pragma unroll
      for (int ht = 0; ht < 2; ++ht){
        f32x16 Cg = zero16(), Cu = zero16();
#pragma unroll
        for (int ks = 0; ks < 8; ++ks){
          bf16x8 ag = ldfrag(WB +         ((ht*8 + ks)*64 + lane)*16);
          bf16x8 au = ldfrag(WB + 16384 + ((ht*8 + ks)*64 + lane)*16);
          Cg = mfma32(ag, xf[ks], Cg);
          Cu = mfma32(au, xf[ks], Cu);
        }
#pragma unroll
        for (int s = 0; s < 2; ++s){
          float h[8];
#pragma unroll
          for (int j = 0; j < 8; ++j){
            float gv = Cg[s*8 + j] * gg;
            float uv = Cu[s*8 + j] * gu;
            h[j] = gv * __builtin_amdgcn_rcpf(1.0f + __expf(-gv)) * uv;
          }
          unsigned w0 = pk2(h[0], h[1]);
          unsigned w1 = pk2(h[2], h[3]);
          unsigned w2 = pk2(h[4], h[5]);
          unsigned w3 = pk2(h[6], h[7]);
          swap32(w0, w2);
          swap32(w1, w3);
          U4 u{w0, w1, w2, w3};
          hf[ht*2 + s] = __builtin_bit_cast(bf16x8, u);
        }
      }

      // mm2: O^T += W_down(d128 x h64) * hidden^T(h64 x t32)
#pragma unroll
      for (int ks2 = 0; ks2 < 4; ++ks2){
        bf16x8 d0 = ldfrag(WB + 32768 + ((0*4 + ks2)*64 + lane)*16);
        bf16x8 d1 = ldfrag(WB + 32768 + ((1*4 + ks2)*64 + lane)*16);
        bf16x8 d2 = ldfrag(WB + 32768 + ((2*4 + ks2)*64 + lane)*16);
        bf16x8 d3 = ldfrag(WB + 32768 + ((3*4 + ks2)*64 + lane)*16);
        O0 = mfma32(d0, hf[ks2], O0);
        O1 = mfma32(d1, hf[ks2], O1);
        O2 = mfma32(d2, hf[ks2], O2);
        O3 = mfma32(d3, hf[ks2], O3);
      }
    }
  }

  // ---- epilogue: lane holds one token, 64 d-values; float4 stores ----
  const float osc = gdn * ew[token * 8 + e];
  float* orow = out + ((size_t)token * 8 + e) * 128 + hi * 4;
#pragma unroll
  for (int dt = 0; dt < 4; ++dt){
    const f32x16& O = dt == 0 ? O0 : dt == 1 ? O1 : dt == 2 ? O2 : O3;
#pragma unroll
    for (int q = 0; q < 4; ++q){
      float4 v{O[q*4+0]*osc, O[q*4+1]*osc, O[q*4+2]*osc, O[q*4+3]*osc};
      *(float4*)(orow + dt * 32 + q * 8) = v;   // d = dt*32 + q*8 + hi*4 + j
    }
  }
}

// ---------------- launcher ----------------
extern "C" void kernel_launch(void* const* d_in, const int* in_sizes, int n_in,
                              void* d_out, int out_size, void* d_ws, size_t ws_size,
                              hipStream_t stream){
  const float* x  = (const float*)d_in[0];
  const float* ew = (const float*)d_in[1];
  const float* gw = (const float*)d_in[2];
  const float* uw = (const float*)d_in[3];
  const float* dw = (const float*)d_in[4];
  float* out = (float*)d_out;

  float* sums = (float*)d_ws;
  unsigned char* img = (unsigned char*)d_ws + 256;

  hipMemsetAsync(d_ws, 0, 16, stream);
  k_gamma<<<dim3(256, 3), 256, 0, stream>>>(gw, uw, dw, sums);
  k_quant<<<dim3(192), 256, 0, stream>>>(gw, uw, dw, sums, img);
  k_moe<<<dim3(64, 8), 512, 98304, stream>>>(x, ew, sums, img, out);
}

// Round 11
// 210.705 us; speedup vs baseline: 1.0580x; 1.0580x over previous
//
#include <hip/hip_runtime.h>

// ---------------- types ----------------
typedef __attribute__((ext_vector_type(8)))  __bf16 bf16x8;
typedef __attribute__((ext_vector_type(16))) float  f32x16;

struct U4 { unsigned int x, y, z, w; };

// pack two floats to bf16x2 (compiler fuses to v_cvt_pk_bf16_f32, RNE)
static __device__ __forceinline__ unsigned pk2(float lo, float hi){
  unsigned short ul = __builtin_bit_cast(unsigned short, (__bf16)lo);
  unsigned short uh = __builtin_bit_cast(unsigned short, (__bf16)hi);
  return (unsigned)ul | ((unsigned)uh << 16);
}

static __device__ __forceinline__ bf16x8 ldfrag(const void* p){
  U4 v = *(const U4*)p;                      // ds_read_b128
  return __builtin_bit_cast(bf16x8, v);
}

static __device__ __forceinline__ f32x16 mfma32(bf16x8 a, bf16x8 b, f32x16 c){
  return __builtin_amdgcn_mfma_f32_32x32x16_bf16(a, b, c, 0, 0, 0);
}

static __device__ __forceinline__ f32x16 zero16(){
  f32x16 z;
#pragma unroll
  for (int i = 0; i < 16; ++i) z[i] = 0.0f;
  return z;
}

// half-wave swap via permlane (VALU-only, no LDS)
static __device__ __forceinline__ void swap32(unsigned &a, unsigned &b){
  asm volatile("v_permlane32_swap_b32 %0, %1" : "+v"(a), "+v"(b));
}

// ---------------- constants ----------------
// B=8 T=2048 E=8 D=128 H=512 ; token-expert rows = 131072
#define IMG_EC  49152           // 48 KB per (expert, chunk): wg 16K | wu 16K | wd 16K

// ---------------- P1: absmean sums ----------------
__global__ void k_gamma(const float* __restrict__ gw, const float* __restrict__ uw,
                        const float* __restrict__ dw, float* __restrict__ sums){
  int t = blockIdx.y;
  const float* w = (t == 0) ? gw : (t == 1 ? uw : dw);
  int base = blockIdx.x * 2048 + threadIdx.x * 8;
  float4 a = *(const float4*)(w + base);
  float4 b = *(const float4*)(w + base + 4);
  float s = fabsf(a.x)+fabsf(a.y)+fabsf(a.z)+fabsf(a.w)
          + fabsf(b.x)+fabsf(b.y)+fabsf(b.z)+fabsf(b.w);
#pragma unroll
  for (int o = 32; o; o >>= 1) s += __shfl_xor(s, o);
  if ((threadIdx.x & 63) == 0) atomicAdd(&sums[t], s);
}

// ---------------- P2: ternary quantize -> fragment-ordered bf16 images ----------------
// gate/up image per (e,c): [ht(2)][ks(8)][lane(64)][16B]  (frag: h = ht*32+(L&31), k d = ks*16+(L>>5)*8+j)
// down    image per (e,c): [dt(4)][ksp(4)][lane(64)][16B] (frag: d = dt*32+(L&31), k h = c*64+ksp*16+(L>>5)*8+j)
__global__ void k_quant(const float* __restrict__ gw, const float* __restrict__ uw,
                        const float* __restrict__ dw, const float* __restrict__ sums,
                        unsigned char* __restrict__ img){
  int b  = blockIdx.x;
  int tt = b % 3;
  int c  = (b / 3) & 7;
  int e  = b / 24;
  const float* w = (tt == 0) ? gw : (tt == 1 ? uw : dw);
  float inv = 1.0f / (sums[tt] * (1.0f / 524288.0f) + 1e-8f);
  unsigned char* dst = img + (size_t)(e * 8 + c) * IMG_EC + tt * 16384;
#pragma unroll
  for (int i = 0; i < 4; ++i){
    int grp = threadIdx.x + i * 256;      // 0..1023 (16B groups of 16KB)
    int L = grp & 63, blkid = grp >> 6;
    int srcoff;
    if (tt < 2){
      int ht = blkid >> 3, ks = blkid & 7;
      int h  = c * 64 + ht * 32 + (L & 31);
      int dd = ks * 16 + (L >> 5) * 8;
      srcoff = (e * 512 + h) * 128 + dd;
    } else {
      int dt = blkid >> 2, ksp = blkid & 3;
      int d0 = dt * 32 + (L & 31);
      int h  = c * 64 + ksp * 16 + (L >> 5) * 8;
      srcoff = (e * 128 + d0) * 512 + h;
    }
    float4 f0 = *(const float4*)(w + srcoff);
    float4 f1 = *(const float4*)(w + srcoff + 4);
    float v[8] = {f0.x,f0.y,f0.z,f0.w,f1.x,f1.y,f1.z,f1.w};
    unsigned int o[4];
#pragma unroll
    for (int j = 0; j < 4; ++j){
      float q0 = fminf(1.0f, fmaxf(-1.0f, rintf(v[2*j]   * inv)));
      float q1 = fminf(1.0f, fmaxf(-1.0f, rintf(v[2*j+1] * inv)));
      o[j] = pk2(q0, q1);
    }
    *(U4*)(dst + grp * 16) = U4{o[0], o[1], o[2], o[3]};
  }
}

// ---------------- main fused kernel ----------------
// grid (64, 8), 512 threads (8 waves), wave owns 32 tokens.
// Swapped mm1: C = mfma(W, x^T) -> col = token; hidden stays in registers
// (cvt_pk + permlane32_swap) feeding mm2 B-frags directly.
// 2-chunk phases, ds_write-only staging (NO global_load_lds: DMA itself
// generates ~3.8e7 bank conflicts even barrier-isolated, R10). One isolated
// write phase stages chunks 2p,2p+1 from stg[12]; compute runs both
// back-to-back while chunks 2p+2,2p+3 load into stg. Barriers 16->8.
// (2,2)+512thr+ds_write-only: the only clean register regime (R6: VGPR 88,
// WRITE exactly 65.5MB; every other attribute or DMA-hybrid spilled).
__global__ __attribute__((amdgpu_waves_per_eu(2, 2))) __launch_bounds__(512)
void k_moe(const float* __restrict__ x, const float* __restrict__ ew,
           const float* __restrict__ sums, const unsigned char* __restrict__ img,
           float* __restrict__ out){
  extern __shared__ char smem[];          // [0,48K) even chunk | [48K,96K) odd
  const int tile = blockIdx.x;
  const int e    = blockIdx.y;
  const int tid  = threadIdx.x;
  const int lane = tid & 63;
  const int wid  = tid >> 6;
  const int col  = lane & 31;
  const int hi   = lane >> 5;
  const int token = tile * 256 + wid * 32 + col;

  const float gg  = sums[0] * (1.0f/524288.0f) + 1e-8f;
  const float gu  = sums[1] * (1.0f/524288.0f) + 1e-8f;
  const float gdn = sums[2] * (1.0f/524288.0f) + 1e-8f;

  const unsigned char* wsrc0 = img + (size_t)e * 8 * IMG_EC;

  // ---- preload chunks 0,1 into stg (12 x 16B per thread = 96KB block) ----
  U4 stg[12];
#pragma unroll
  for (int k = 0; k < 12; ++k)
    stg[k] = *(const U4*)(wsrc0 + tid * 16 + k * 8192);   // 2 chunks contiguous

  // ---- x fragments in registers: lane holds x[token][ks*16 + hi*8 .. +8) ----
  const float* xrow = x + ((size_t)token * 8 + e) * 128 + hi * 8;
  bf16x8 xf[8];
#pragma unroll
  for (int ks = 0; ks < 8; ++ks){
    float4 f0 = *(const float4*)(xrow + ks * 16);
    float4 f1 = *(const float4*)(xrow + ks * 16 + 4);
    U4 u{pk2(f0.x,f0.y), pk2(f0.z,f0.w), pk2(f1.x,f1.y), pk2(f1.z,f1.w)};
    xf[ks] = __builtin_bit_cast(bf16x8, u);
  }

  f32x16 O0 = zero16(), O1 = zero16(), O2 = zero16(), O3 = zero16();

  for (int p = 0; p < 4; ++p){
    // ---- write phase: stage BOTH chunks, barrier-isolated from reads ----
    if (p) __syncthreads();               // compute(p-1) done reading smem
#pragma unroll
    for (int k = 0; k < 12; ++k)
      *(U4*)(smem + tid * 16 + k * 8192) = stg[k];
    __syncthreads();                      // both buffers ready

    // ---- issue loads for chunks 2p+2, 2p+3; hidden under double-compute ----
    if (p < 3){
      const unsigned char* cs = wsrc0 + (size_t)(2 * p + 2) * IMG_EC;
#pragma unroll
      for (int k = 0; k < 12; ++k)
        stg[k] = *(const U4*)(cs + tid * 16 + k * 8192);
    }

    // ---- compute chunks 2p (half=0) and 2p+1 (half=1) back-to-back ----
#pragma unroll
    for (int half = 0; half < 2; ++half){
      const char* WB = smem + half * 49152;

      // mm1 per 32-h half + silu -> hf (in-register hidden)
      bf16x8 hf[4];
#pragma unroll
      for (int ht = 0; ht < 2; ++ht){
        f32x16 Cg = zero16(), Cu = zero16();
#pragma unroll
        for (int ks = 0; ks < 8; ++ks){
          bf16x8 ag = ldfrag(WB +         ((ht*8 + ks)*64 + lane)*16);
          bf16x8 au = ldfrag(WB + 16384 + ((ht*8 + ks)*64 + lane)*16);
          Cg = mfma32(ag, xf[ks], Cg);
          Cu = mfma32(au, xf[ks], Cu);
        }
#pragma unroll
        for (int s = 0; s < 2; ++s){
          float h[8];
#pragma unroll
          for (int j = 0; j < 8; ++j){
            float gv = Cg[s*8 + j] * gg;
            float uv = Cu[s*8 + j] * gu;
            h[j] = gv * __builtin_amdgcn_rcpf(1.0f + __expf(-gv)) * uv;
          }
          unsigned w0 = pk2(h[0], h[1]);
          unsigned w1 = pk2(h[2], h[3]);
          unsigned w2 = pk2(h[4], h[5]);
          unsigned w3 = pk2(h[6], h[7]);
          swap32(w0, w2);
          swap32(w1, w3);
          U4 u{w0, w1, w2, w3};
          hf[ht*2 + s] = __builtin_bit_cast(bf16x8, u);
        }
      }

      // mm2: O^T += W_down(d128 x h64) * hidden^T(h64 x t32)
#pragma unroll
      for (int ks2 = 0; ks2 < 4; ++ks2){
        bf16x8 d0 = ldfrag(WB + 32768 + ((0*4 + ks2)*64 + lane)*16);
        bf16x8 d1 = ldfrag(WB + 32768 + ((1*4 + ks2)*64 + lane)*16);
        bf16x8 d2 = ldfrag(WB + 32768 + ((2*4 + ks2)*64 + lane)*16);
        bf16x8 d3 = ldfrag(WB + 32768 + ((3*4 + ks2)*64 + lane)*16);
        O0 = mfma32(d0, hf[ks2], O0);
        O1 = mfma32(d1, hf[ks2], O1);
        O2 = mfma32(d2, hf[ks2], O2);
        O3 = mfma32(d3, hf[ks2], O3);
      }
    }
  }

  // ---- epilogue: lane holds one token, 64 d-values; float4 stores ----
  const float osc = gdn * ew[token * 8 + e];
  float* orow = out + ((size_t)token * 8 + e) * 128 + hi * 4;
#pragma unroll
  for (int dt = 0; dt < 4; ++dt){
    const f32x16& O = dt == 0 ? O0 : dt == 1 ? O1 : dt == 2 ? O2 : O3;
#pragma unroll
    for (int q = 0; q < 4; ++q){
      float4 v{O[q*4+0]*osc, O[q*4+1]*osc, O[q*4+2]*osc, O[q*4+3]*osc};
      *(float4*)(orow + dt * 32 + q * 8) = v;   // d = dt*32 + q*8 + hi*4 + j
    }
  }
}

// ---------------- launcher ----------------
extern "C" void kernel_launch(void* const* d_in, const int* in_sizes, int n_in,
                              void* d_out, int out_size, void* d_ws, size_t ws_size,
                              hipStream_t stream){
  const float* x  = (const float*)d_in[0];
  const float* ew = (const float*)d_in[1];
  const float* gw = (const float*)d_in[2];
  const float* uw = (const float*)d_in[3];
  const float* dw = (const float*)d_in[4];
  float* out = (float*)d_out;

  float* sums = (float*)d_ws;
  unsigned char* img = (unsigned char*)d_ws + 256;

  hipMemsetAsync(d_ws, 0, 16, stream);
  k_gamma<<<dim3(256, 3), 256, 0, stream>>>(gw, uw, dw, sums);
  k_quant<<<dim3(192), 256, 0, stream>>>(gw, uw, dw, sums, img);
  k_moe<<<dim3(64, 8), 512, 98304, stream>>>(x, ew, sums, img, out);
}

// Round 12
// 175.131 us; speedup vs baseline: 1.2729x; 1.2031x over previous
//
#include <hip/hip_runtime.h>

// ---------------- types ----------------
typedef __attribute__((ext_vector_type(8)))  __bf16 bf16x8;
typedef __attribute__((ext_vector_type(16))) float  f32x16;

struct U4 { unsigned int x, y, z, w; };

// pack two floats to bf16x2 (compiler fuses to v_cvt_pk_bf16_f32, RNE)
static __device__ __forceinline__ unsigned pk2(float lo, float hi){
  unsigned short ul = __builtin_bit_cast(unsigned short, (__bf16)lo);
  unsigned short uh = __builtin_bit_cast(unsigned short, (__bf16)hi);
  return (unsigned)ul | ((unsigned)uh << 16);
}

static __device__ __forceinline__ bf16x8 ldfrag(const void* p){
  U4 v = *(const U4*)p;                      // global_load_dwordx4 (L2-resident)
  return __builtin_bit_cast(bf16x8, v);
}

static __device__ __forceinline__ f32x16 mfma32(bf16x8 a, bf16x8 b, f32x16 c){
  return __builtin_amdgcn_mfma_f32_32x32x16_bf16(a, b, c, 0, 0, 0);
}

static __device__ __forceinline__ f32x16 zero16(){
  f32x16 z;
#pragma unroll
  for (int i = 0; i < 16; ++i) z[i] = 0.0f;
  return z;
}

// half-wave swap via permlane (VALU-only, no LDS)
static __device__ __forceinline__ void swap32(unsigned &a, unsigned &b){
  asm volatile("v_permlane32_swap_b32 %0, %1" : "+v"(a), "+v"(b));
}

// ---------------- constants ----------------
// B=8 T=2048 E=8 D=128 H=512 ; token-expert rows = 131072
#define IMG_EC  49152           // 48 KB per (expert, chunk): wg 16K | wu 16K | wd 16K

// ---------------- P1: absmean sums ----------------
__global__ void k_gamma(const float* __restrict__ gw, const float* __restrict__ uw,
                        const float* __restrict__ dw, float* __restrict__ sums){
  int t = blockIdx.y;
  const float* w = (t == 0) ? gw : (t == 1 ? uw : dw);
  int base = blockIdx.x * 2048 + threadIdx.x * 8;
  float4 a = *(const float4*)(w + base);
  float4 b = *(const float4*)(w + base + 4);
  float s = fabsf(a.x)+fabsf(a.y)+fabsf(a.z)+fabsf(a.w)
          + fabsf(b.x)+fabsf(b.y)+fabsf(b.z)+fabsf(b.w);
#pragma unroll
  for (int o = 32; o; o >>= 1) s += __shfl_xor(s, o);
  if ((threadIdx.x & 63) == 0) atomicAdd(&sums[t], s);
}

// ---------------- P2: ternary quantize -> fragment-ordered bf16 images ----------------
// gate/up image per (e,c): [ht(2)][ks(8)][lane(64)][16B]  (frag: h = ht*32+(L&31), k d = ks*16+(L>>5)*8+j)
// down    image per (e,c): [dt(4)][ksp(4)][lane(64)][16B] (frag: d = dt*32+(L&31), k h = c*64+ksp*16+(L>>5)*8+j)
__global__ void k_quant(const float* __restrict__ gw, const float* __restrict__ uw,
                        const float* __restrict__ dw, const float* __restrict__ sums,
                        unsigned char* __restrict__ img){
  int b  = blockIdx.x;
  int tt = b % 3;
  int c  = (b / 3) & 7;
  int e  = b / 24;
  const float* w = (tt == 0) ? gw : (tt == 1 ? uw : dw);
  float inv = 1.0f / (sums[tt] * (1.0f / 524288.0f) + 1e-8f);
  unsigned char* dst = img + (size_t)(e * 8 + c) * IMG_EC + tt * 16384;
#pragma unroll
  for (int i = 0; i < 4; ++i){
    int grp = threadIdx.x + i * 256;      // 0..1023 (16B groups of 16KB)
    int L = grp & 63, blkid = grp >> 6;
    int srcoff;
    if (tt < 2){
      int ht = blkid >> 3, ks = blkid & 7;
      int h  = c * 64 + ht * 32 + (L & 31);
      int dd = ks * 16 + (L >> 5) * 8;
      srcoff = (e * 512 + h) * 128 + dd;
    } else {
      int dt = blkid >> 2, ksp = blkid & 3;
      int d0 = dt * 32 + (L & 31);
      int h  = c * 64 + ksp * 16 + (L >> 5) * 8;
      srcoff = (e * 128 + d0) * 512 + h;
    }
    float4 f0 = *(const float4*)(w + srcoff);
    float4 f1 = *(const float4*)(w + srcoff + 4);
    float v[8] = {f0.x,f0.y,f0.z,f0.w,f1.x,f1.y,f1.z,f1.w};
    unsigned int o[4];
#pragma unroll
    for (int j = 0; j < 4; ++j){
      float q0 = fminf(1.0f, fmaxf(-1.0f, rintf(v[2*j]   * inv)));
      float q1 = fminf(1.0f, fmaxf(-1.0f, rintf(v[2*j+1] * inv)));
      o[j] = pk2(q0, q1);
    }
    *(U4*)(dst + grp * 16) = U4{o[0], o[1], o[2], o[3]};
  }
}

// ---------------- main fused kernel ----------------
// grid (128, 8), 256 threads (4 waves), wave owns 32 tokens. NO LDS, NO
// barriers: weight fragments are loaded straight from the L2-resident image
// (3MB < 4MB per-XCD L2; each block's reuse is only 8 same-address waves ->
// L1/L2 serve it; LDS staging was pure overhead: write phases + lockstep
// barriers (64% stall, R6) + staging regs (the R5/R8-R11 spill demon) +
// DMA/wide-write conflicts). Free-running waves, 4 indep MFMA chains each.
// (2,2) keeps the proven no-spill register regime; 2 blocks/CU resident.
__global__ __attribute__((amdgpu_waves_per_eu(2, 2))) __launch_bounds__(256)
void k_moe(const float* __restrict__ x, const float* __restrict__ ew,
           const float* __restrict__ sums, const unsigned char* __restrict__ img,
           float* __restrict__ out){
  const int tile = blockIdx.x;
  const int e    = blockIdx.y;
  const int tid  = threadIdx.x;
  const int lane = tid & 63;
  const int wid  = tid >> 6;            // 0..3
  const int col  = lane & 31;
  const int hi   = lane >> 5;
  const int token = tile * 128 + wid * 32 + col;

  const float gg  = sums[0] * (1.0f/524288.0f) + 1e-8f;
  const float gu  = sums[1] * (1.0f/524288.0f) + 1e-8f;
  const float gdn = sums[2] * (1.0f/524288.0f) + 1e-8f;

  // ---- x fragments in registers: lane holds x[token][ks*16 + hi*8 .. +8) ----
  const float* xrow = x + ((size_t)token * 8 + e) * 128 + hi * 8;
  bf16x8 xf[8];
#pragma unroll
  for (int ks = 0; ks < 8; ++ks){
    float4 f0 = *(const float4*)(xrow + ks * 16);
    float4 f1 = *(const float4*)(xrow + ks * 16 + 4);
    U4 u{pk2(f0.x,f0.y), pk2(f0.z,f0.w), pk2(f1.x,f1.y), pk2(f1.z,f1.w)};
    xf[ks] = __builtin_bit_cast(bf16x8, u);
  }

  f32x16 O0 = zero16(), O1 = zero16(), O2 = zero16(), O3 = zero16();

  // per-lane base into the fragment image: all hot-loop addresses are
  // wl + compile-time-constant offsets (coalesced 1KB/wave dwordx4 loads)
  const unsigned char* wl = img + (size_t)e * 8 * IMG_EC + lane * 16;

  for (int c = 0; c < 8; ++c){
    const unsigned char* wc = wl + (size_t)c * IMG_EC;

    // ---- mm1 per 32-h half + silu -> hf (in-register hidden) ----
    bf16x8 hf[4];
#pragma unroll
    for (int ht = 0; ht < 2; ++ht){
      f32x16 Cg = zero16(), Cu = zero16();
#pragma unroll
      for (int ks = 0; ks < 8; ++ks){
        bf16x8 ag = ldfrag(wc +         (ht*8 + ks) * 1024);
        bf16x8 au = ldfrag(wc + 16384 + (ht*8 + ks) * 1024);
        Cg = mfma32(ag, xf[ks], Cg);
        Cu = mfma32(au, xf[ks], Cu);
      }
#pragma unroll
      for (int s = 0; s < 2; ++s){
        float h[8];
#pragma unroll
        for (int j = 0; j < 8; ++j){
          float gv = Cg[s*8 + j] * gg;
          float uv = Cu[s*8 + j] * gu;
          h[j] = gv * __builtin_amdgcn_rcpf(1.0f + __expf(-gv)) * uv;
        }
        unsigned w0 = pk2(h[0], h[1]);
        unsigned w1 = pk2(h[2], h[3]);
        unsigned w2 = pk2(h[4], h[5]);
        unsigned w3 = pk2(h[6], h[7]);
        swap32(w0, w2);
        swap32(w1, w3);
        U4 u{w0, w1, w2, w3};
        hf[ht*2 + s] = __builtin_bit_cast(bf16x8, u);
      }
    }

    // ---- mm2: O^T += W_down(d128 x h64) * hidden^T(h64 x t32) ----
#pragma unroll
    for (int ks2 = 0; ks2 < 4; ++ks2){
      bf16x8 d0 = ldfrag(wc + 32768 + (0*4 + ks2) * 1024);
      bf16x8 d1 = ldfrag(wc + 32768 + (1*4 + ks2) * 1024);
      bf16x8 d2 = ldfrag(wc + 32768 + (2*4 + ks2) * 1024);
      bf16x8 d3 = ldfrag(wc + 32768 + (3*4 + ks2) * 1024);
      O0 = mfma32(d0, hf[ks2], O0);
      O1 = mfma32(d1, hf[ks2], O1);
      O2 = mfma32(d2, hf[ks2], O2);
      O3 = mfma32(d3, hf[ks2], O3);
    }
  }

  // ---- epilogue: lane holds one token, 64 d-values; float4 stores ----
  const float osc = gdn * ew[token * 8 + e];
  float* orow = out + ((size_t)token * 8 + e) * 128 + hi * 4;
#pragma unroll
  for (int dt = 0; dt < 4; ++dt){
    const f32x16& O = dt == 0 ? O0 : dt == 1 ? O1 : dt == 2 ? O2 : O3;
#pragma unroll
    for (int q = 0; q < 4; ++q){
      float4 v{O[q*4+0]*osc, O[q*4+1]*osc, O[q*4+2]*osc, O[q*4+3]*osc};
      *(float4*)(orow + dt * 32 + q * 8) = v;   // d = dt*32 + q*8 + hi*4 + j
    }
  }
}

// ---------------- launcher ----------------
extern "C" void kernel_launch(void* const* d_in, const int* in_sizes, int n_in,
                              void* d_out, int out_size, void* d_ws, size_t ws_size,
                              hipStream_t stream){
  const float* x  = (const float*)d_in[0];
  const float* ew = (const float*)d_in[1];
  const float* gw = (const float*)d_in[2];
  const float* uw = (const float*)d_in[3];
  const float* dw = (const float*)d_in[4];
  float* out = (float*)d_out;

  float* sums = (float*)d_ws;
  unsigned char* img = (unsigned char*)d_ws + 256;

  hipMemsetAsync(d_ws, 0, 16, stream);
  k_gamma<<<dim3(256, 3), 256, 0, stream>>>(gw, uw, dw, sums);
  k_quant<<<dim3(192), 256, 0, stream>>>(gw, uw, dw, sums, img);
  k_moe<<<dim3(128, 8), 256, 0, stream>>>(x, ew, sums, img, out);
}